// Round 1
// baseline (8129.994 us; speedup 1.0000x reference)
//
#include <hip/hip_runtime.h>
#include <math.h>

#define HID   256
#define SEQ   512
#define BATCH 256
#define NPRED 64
#define NOUT  3
#define KCAT  515   // 3 (x_in) + 256 (ctx) + 256 (h)
#define GATES 1024

__device__ __forceinline__ float sigmoidf_(float x) { return 1.0f / (1.0f + __expf(-x)); }
__device__ __forceinline__ float tanh_(float x)     { return 1.0f - 2.0f / (__expf(2.0f * x) + 1.0f); }

// ---------------------------------------------------------------------------
// Prep: build transposed weight layouts in workspace so the per-step GEMVs
// read coalesced (thread t reads column t / float4 columns).
//   WaT[k][j]   = Wa[j][k]                      (wq[j] = sum_k WaT[k][j] h[k])
//   WcatT[k][j] = k<259 ? W_ih[j][k] : W_hh[j][k-259]
//   bias_g[j]   = b_ih[j] + b_hh[j]
// ---------------------------------------------------------------------------
__global__ void prep_kernel(const float* __restrict__ Wa,
                            const float* __restrict__ W_ih,
                            const float* __restrict__ W_hh,
                            const float* __restrict__ b_ih,
                            const float* __restrict__ b_hh,
                            float* __restrict__ WaT,
                            float* __restrict__ WcatT,
                            float* __restrict__ bias_g) {
    const int idx = blockIdx.x * blockDim.x + threadIdx.x;
    if (idx < HID * HID) {
        const int k = idx >> 8, j = idx & 255;
        WaT[idx] = Wa[j * HID + k];
    }
    if (idx < KCAT * GATES) {
        const int k = idx >> 10, j = idx & 1023;
        WcatT[idx] = (k < 259) ? W_ih[j * 259 + k] : W_hh[j * HID + (k - 259)];
    }
    if (idx < GATES) bias_g[idx] = b_ih[idx] + b_hh[idx];
}

// ---------------------------------------------------------------------------
// Persistent decoder: one block per batch element, full 64-step recurrence,
// no inter-block communication.
// ---------------------------------------------------------------------------
__global__ __launch_bounds__(256)
void decoder_kernel(const float* __restrict__ enc,     // [B,S,H]
                    const float* __restrict__ h0,      // [1,B,H]
                    const float* __restrict__ c0,      // [1,B,H]
                    const float* __restrict__ ba,      // [H]
                    const float* __restrict__ Ua,      // [H,H] row-major
                    const float* __restrict__ bua,     // [H]
                    const float* __restrict__ Wo,      // [3,H]
                    const float* __restrict__ bo,      // [3]
                    const float* __restrict__ WaT,     // [H,H]
                    const float* __restrict__ WcatT,   // [515,1024]
                    const float* __restrict__ bias_g,  // [1024]
                    float* __restrict__ pred_out,      // [B,N,3]
                    float* __restrict__ hid_out,       // [B,H]
                    float* __restrict__ attn_out)      // [B,N,S]
{
    const int b    = blockIdx.x;
    const int t    = threadIdx.x;
    const int wave = t >> 6;
    const int lane = t & 63;

    __shared__ __align__(16) float s_h[HID];
    __shared__ __align__(16) float s_c[HID];
    __shared__ __align__(16) float s_wq[HID];
    __shared__ __align__(16) float s_vq[HID];
    __shared__ __align__(16) float s_xcat[KCAT + 1];   // [x_in(3) | ctx(256) | h(256)]
    __shared__ __align__(16) float s_gates[GATES];
    __shared__ __align__(16) float s_scores[SEQ];
    __shared__ __align__(16) float s_wctx[4][HID];
    __shared__ float s_wm[4], s_wl[4], s_red[4];

    // init state
    s_h[t] = h0[b * HID + t];
    s_c[t] = c0[b * HID + t];
    s_xcat[259 + t] = s_h[t];
    if (t < NOUT) s_xcat[t] = 0.0f;   // SOS token = 0
    __syncthreads();

    const float* encb = enc + (size_t)b * SEQ * HID;

    for (int n = 0; n < NPRED; ++n) {
        // ---- Phase 1: wq[t] = sum_k Wa[t][k] h[k] + ba[t] (via WaT) ----
        float wqt = ba[t];
        #pragma unroll 8
        for (int k = 0; k < HID; ++k)
            wqt += WaT[k * HID + t] * s_h[k];
        s_wq[t] = wqt;
        __syncthreads();

        // ---- Phase 2: vq[t] = sum_h wq[h] Ua[h][t];  tb = wq . bua ----
        float vacc = 0.0f;
        #pragma unroll 8
        for (int k = 0; k < HID; ++k)
            vacc += s_wq[k] * Ua[k * HID + t];
        s_vq[t] = vacc;
        float pb = wqt * bua[t];
        #pragma unroll
        for (int off = 32; off >= 1; off >>= 1) pb += __shfl_xor(pb, off);
        if (lane == 0) s_red[wave] = pb;
        __syncthreads();
        const float tb = s_red[0] + s_red[1] + s_red[2] + s_red[3];

        // ---- Phase 3: one pass over enc[b]: scores + online-softmax ctx ----
        const float4 vq4 = *(const float4*)&s_vq[lane * 4];
        float m = -INFINITY, lsum = 0.0f;
        float4 cacc = {0.f, 0.f, 0.f, 0.f};
        for (int s = wave; s < SEQ; s += 4) {
            const float4 e4 = *(const float4*)&encb[s * HID + lane * 4];
            float p = e4.x * vq4.x + e4.y * vq4.y + e4.z * vq4.z + e4.w * vq4.w;
            #pragma unroll
            for (int off = 32; off >= 1; off >>= 1) p += __shfl_xor(p, off);
            const float score = p + tb;          // every lane has the full sum
            if (lane == 0) s_scores[s] = score;
            const float mnew  = fmaxf(m, score);
            const float alpha = __expf(m - mnew);   // first iter: exp(-inf)=0
            const float e     = __expf(score - mnew);
            lsum   = lsum * alpha + e;
            cacc.x = cacc.x * alpha + e4.x * e;
            cacc.y = cacc.y * alpha + e4.y * e;
            cacc.z = cacc.z * alpha + e4.z * e;
            cacc.w = cacc.w * alpha + e4.w * e;
            m = mnew;
        }
        *(float4*)&s_wctx[wave][lane * 4] = cacc;
        if (lane == 0) { s_wm[wave] = m; s_wl[wave] = lsum; }
        __syncthreads();

        // ---- combine wave partials; write ctx + attention weights ----
        const float M  = fmaxf(fmaxf(s_wm[0], s_wm[1]), fmaxf(s_wm[2], s_wm[3]));
        const float a0 = __expf(s_wm[0] - M), a1 = __expf(s_wm[1] - M);
        const float a2 = __expf(s_wm[2] - M), a3 = __expf(s_wm[3] - M);
        const float L  = s_wl[0] * a0 + s_wl[1] * a1 + s_wl[2] * a2 + s_wl[3] * a3;
        const float invL = 1.0f / L;
        s_xcat[3 + t] = (s_wctx[0][t] * a0 + s_wctx[1][t] * a1 +
                         s_wctx[2][t] * a2 + s_wctx[3][t] * a3) * invL;
        float* attn_b = attn_out + ((size_t)b * NPRED + n) * SEQ;
        attn_b[t]       = __expf(s_scores[t]       - M) * invL;
        attn_b[t + 256] = __expf(s_scores[t + 256] - M) * invL;
        __syncthreads();

        // ---- Phase 5: gates[4t..4t+3] = bias + sum_k WcatT[k][4t..] xcat[k] ----
        float4 g4 = *(const float4*)&bias_g[t * 4];
        #pragma unroll 5
        for (int k = 0; k < KCAT; ++k) {
            const float xk = s_xcat[k];
            const float4 w4 = *(const float4*)&WcatT[k * GATES + t * 4];
            g4.x += xk * w4.x; g4.y += xk * w4.y; g4.z += xk * w4.z; g4.w += xk * w4.w;
        }
        *(float4*)&s_gates[t * 4] = g4;
        __syncthreads();

        // ---- Phase 6: LSTM pointwise (unit t); torch gate order i,f,g,o ----
        {
            const float gi = s_gates[t];
            const float gf = s_gates[256 + t];
            const float gg = s_gates[512 + t];
            const float go = s_gates[768 + t];
            const float cn = sigmoidf_(gf) * s_c[t] + sigmoidf_(gi) * tanh_(gg);
            const float hn = sigmoidf_(go) * tanh_(cn);
            s_c[t] = cn;
            s_h[t] = hn;
            s_xcat[259 + t] = hn;
        }
        __syncthreads();

        // ---- Phase 7: pred[o] = Wo[o] . h + bo[o]; feedback as next x_in ----
        if (wave < NOUT) {
            const float4 w4 = *(const float4*)&Wo[wave * HID + lane * 4];
            const float4 h4 = *(const float4*)&s_h[lane * 4];
            float p = w4.x * h4.x + w4.y * h4.y + w4.z * h4.z + w4.w * h4.w;
            #pragma unroll
            for (int off = 32; off >= 1; off >>= 1) p += __shfl_xor(p, off);
            if (lane == 0) {
                p += bo[wave];
                s_xcat[wave] = p;
                pred_out[((size_t)b * NPRED + n) * NOUT + wave] = p;
            }
        }
        __syncthreads();
    }

    hid_out[b * HID + t] = s_h[t];
}

// ---------------------------------------------------------------------------
extern "C" void kernel_launch(void* const* d_in, const int* in_sizes, int n_in,
                              void* d_out, int out_size, void* d_ws, size_t ws_size,
                              hipStream_t stream) {
    const float* enc  = (const float*)d_in[0];
    const float* h0   = (const float*)d_in[1];
    const float* c0   = (const float*)d_in[2];
    const float* Wa   = (const float*)d_in[3];
    const float* ba   = (const float*)d_in[4];
    const float* Ua   = (const float*)d_in[5];
    const float* bua  = (const float*)d_in[6];
    const float* W_ih = (const float*)d_in[7];
    const float* W_hh = (const float*)d_in[8];
    const float* b_ih = (const float*)d_in[9];
    const float* b_hh = (const float*)d_in[10];
    const float* Wo   = (const float*)d_in[11];
    const float* bo   = (const float*)d_in[12];

    float* WaT    = (float*)d_ws;               // 65536 floats
    float* WcatT  = WaT + HID * HID;            // 527360 floats
    float* bias_g = WcatT + KCAT * GATES;       // 1024 floats  (~2.27 MB total)

    float* pred_out = (float*)d_out;                    // [B,N,3]   = 49152
    float* hid_out  = pred_out + BATCH * NPRED * NOUT;  // [1,B,H]   = 65536
    float* attn_out = hid_out + BATCH * HID;            // [B,N,S]   = 8388608

    prep_kernel<<<dim3((KCAT * GATES + 255) / 256), dim3(256), 0, stream>>>(
        Wa, W_ih, W_hh, b_ih, b_hh, WaT, WcatT, bias_g);

    decoder_kernel<<<dim3(BATCH), dim3(256), 0, stream>>>(
        enc, h0, c0, ba, Ua, bua, Wo, bo, WaT, WcatT, bias_g,
        pred_out, hid_out, attn_out);
}

// Round 2
// 4159.795 us; speedup vs baseline: 1.9544x; 1.9544x over previous
//
#include <hip/hip_runtime.h>
#include <math.h>

#define HID   256
#define SEQ   512
#define BATCH 256
#define NPRED 64
#define NOUT  3
#define KCAT  515   // 3 (x_in) + 256 (ctx) + 256 (h)
#define GATES 1024

__device__ __forceinline__ float sigmoidf_(float x) { return 1.0f / (1.0f + __expf(-x)); }
__device__ __forceinline__ float tanh_(float x)     { return 1.0f - 2.0f / (__expf(2.0f * x) + 1.0f); }

// ---------------------------------------------------------------------------
// Prep: transposed weight layouts so per-step GEMVs read coalesced.
//   WaT[k][j]   = Wa[j][k]
//   WcatT[k][j] = k<259 ? W_ih[j][k] : W_hh[j][k-259]
//   bias_g[j]   = b_ih[j] + b_hh[j]
// ---------------------------------------------------------------------------
__global__ void prep_kernel(const float* __restrict__ Wa,
                            const float* __restrict__ W_ih,
                            const float* __restrict__ W_hh,
                            const float* __restrict__ b_ih,
                            const float* __restrict__ b_hh,
                            float* __restrict__ WaT,
                            float* __restrict__ WcatT,
                            float* __restrict__ bias_g) {
    const int idx = blockIdx.x * blockDim.x + threadIdx.x;
    if (idx < HID * HID) {
        const int k = idx >> 8, j = idx & 255;
        WaT[idx] = Wa[j * HID + k];
    }
    if (idx < KCAT * GATES) {
        const int k = idx >> 10, j = idx & 1023;
        WcatT[idx] = (k < 259) ? W_ih[j * 259 + k] : W_hh[j * HID + (k - 259)];
    }
    if (idx < GATES) bias_g[idx] = b_ih[idx] + b_hh[idx];
}

// ---------------------------------------------------------------------------
// Persistent decoder: one 1024-thread block (16 waves) per batch element.
// All GEMV phases use 4-way split-K across thread groups for latency hiding.
// ---------------------------------------------------------------------------
__global__ __launch_bounds__(1024)
void decoder_kernel(const float* __restrict__ enc,     // [B,S,H]
                    const float* __restrict__ h0,      // [1,B,H]
                    const float* __restrict__ c0,      // [1,B,H]
                    const float* __restrict__ ba,      // [H]
                    const float* __restrict__ Ua,      // [H,H] row-major
                    const float* __restrict__ bua,     // [H]
                    const float* __restrict__ Wo,      // [3,H]
                    const float* __restrict__ bo,      // [3]
                    const float* __restrict__ WaT,     // [H,H]
                    const float* __restrict__ WcatT,   // [515,1024]
                    const float* __restrict__ bias_g,  // [1024]
                    float* __restrict__ pred_out,      // [B,N,3]
                    float* __restrict__ hid_out,       // [B,H]
                    float* __restrict__ attn_out)      // [B,N,S]
{
    const int b    = blockIdx.x;
    const int t    = threadIdx.x;
    const int wave = t >> 6;          // 0..15
    const int lane = t & 63;
    const int j    = t & 255;         // output index within 256-wide arrays
    const int ks   = t >> 8;          // 0..3 split-K slice

    __shared__ __align__(16) float s_h[HID], s_c[HID], s_wq[HID], s_vq[HID];
    __shared__ __align__(16) float s_xcat[KCAT + 1];   // [x_in(3) | ctx(256) | h(256)]
    __shared__ __align__(16) float s_scores[SEQ];
    __shared__ __align__(16) float s_gp[4096];   // P3: [16][256] wave-ctx; P5: [4][1024] gate partials
    __shared__ __align__(16) float s_part[4][HID];
    __shared__ float s_wm[16], s_wl[16], s_tbred[4], s_M, s_invL;

    if (t < HID) {
        s_h[t] = h0[b * HID + t];
        s_c[t] = c0[b * HID + t];
        s_xcat[259 + t] = s_h[t];
        if (t < NOUT) s_xcat[t] = 0.0f;   // SOS token = 0
    }
    __syncthreads();

    const float* encb = enc + (size_t)b * SEQ * HID;

    for (int n = 0; n < NPRED; ++n) {
        // ---- P1: wq[j] = ba[j] + sum_k WaT[k][j] h[k]; split-K over 4 slices ----
        {
            float acc = 0.0f;
            const int k0 = ks * 64;
            #pragma unroll 8
            for (int kk = 0; kk < 64; ++kk) {
                const int k = k0 + kk;
                acc += WaT[k * HID + j] * s_h[k];
            }
            s_part[ks][j] = acc;
        }
        __syncthreads();
        if (t < HID)
            s_wq[t] = ba[t] + s_part[0][t] + s_part[1][t] + s_part[2][t] + s_part[3][t];
        __syncthreads();

        // ---- P2: vq[j] = sum_k wq[k] Ua[k][j]; tb = wq . bua ----
        {
            float acc = 0.0f;
            const int k0 = ks * 64;
            #pragma unroll 8
            for (int kk = 0; kk < 64; ++kk) {
                const int k = k0 + kk;
                acc += s_wq[k] * Ua[k * HID + j];
            }
            s_part[ks][j] = acc;
        }
        if (t < HID) {
            float pb = s_wq[t] * bua[t];
            #pragma unroll
            for (int off = 32; off >= 1; off >>= 1) pb += __shfl_xor(pb, off);
            if (lane == 0) s_tbred[wave] = pb;
        }
        __syncthreads();
        if (t < HID)
            s_vq[t] = s_part[0][t] + s_part[1][t] + s_part[2][t] + s_part[3][t];
        const float tb = s_tbred[0] + s_tbred[1] + s_tbred[2] + s_tbred[3];
        __syncthreads();

        // ---- P3: one pass over enc[b]; wave w handles rows w, w+16, ... ----
        const float4 vq4 = *(const float4*)&s_vq[lane * 4];
        float m = -INFINITY, lsum = 0.0f;
        float4 cacc = {0.f, 0.f, 0.f, 0.f};
        for (int s = wave; s < SEQ; s += 16) {
            const float4 e4 = *(const float4*)&encb[s * HID + lane * 4];
            float p = e4.x * vq4.x + e4.y * vq4.y + e4.z * vq4.z + e4.w * vq4.w;
            #pragma unroll
            for (int off = 32; off >= 1; off >>= 1) p += __shfl_xor(p, off);
            const float score = p + tb;
            if (lane == 0) s_scores[s] = score;
            const float mnew  = fmaxf(m, score);
            const float alpha = __expf(m - mnew);   // first iter: exp(-inf)=0
            const float e     = __expf(score - mnew);
            lsum   = lsum * alpha + e;
            cacc.x = cacc.x * alpha + e4.x * e;
            cacc.y = cacc.y * alpha + e4.y * e;
            cacc.z = cacc.z * alpha + e4.z * e;
            cacc.w = cacc.w * alpha + e4.w * e;
            m = mnew;
        }
        *(float4*)&s_gp[wave * HID + lane * 4] = cacc;
        if (lane == 0) { s_wm[wave] = m; s_wl[wave] = lsum; }
        __syncthreads();

        // ---- combine 16 wave partials; write ctx ----
        if (t < HID) {
            float M = s_wm[0];
            #pragma unroll
            for (int w = 1; w < 16; ++w) M = fmaxf(M, s_wm[w]);
            float L = 0.0f, ctx = 0.0f;
            #pragma unroll
            for (int w = 0; w < 16; ++w) {
                const float a = __expf(s_wm[w] - M);
                L   += a * s_wl[w];
                ctx += a * s_gp[w * HID + t];
            }
            const float invL = 1.0f / L;
            s_xcat[3 + t] = ctx * invL;
            if (t == 0) { s_M = M; s_invL = invL; }
        }
        __syncthreads();

        // ---- attention weights out (t < 512); overlaps with P5 issue ----
        if (t < SEQ)
            attn_out[((size_t)b * NPRED + n) * SEQ + t] =
                __expf(s_scores[t] - s_M) * s_invL;

        // ---- P5: gates[4j..4j+3] partials, split-K over 4 slices of 515 ----
        {
            float4 g4 = {0.f, 0.f, 0.f, 0.f};
            const int kbeg = ks * 129;
            const int kend = (ks == 3) ? KCAT : kbeg + 129;
            for (int k = kbeg; k < kend; ++k) {
                const float xk = s_xcat[k];
                const float4 w4 = *(const float4*)&WcatT[k * GATES + j * 4];
                g4.x += xk * w4.x; g4.y += xk * w4.y;
                g4.z += xk * w4.z; g4.w += xk * w4.w;
            }
            *(float4*)&s_gp[ks * GATES + j * 4] = g4;
        }
        __syncthreads();

        // ---- finalize gates + LSTM pointwise (unit t); gate order i,f,g,o ----
        if (t < HID) {
            float gv[4];
            #pragma unroll
            for (int q = 0; q < 4; ++q) {
                const int gi = q * HID + t;
                gv[q] = bias_g[gi] + s_gp[gi] + s_gp[GATES + gi]
                      + s_gp[2 * GATES + gi] + s_gp[3 * GATES + gi];
            }
            const float cn = sigmoidf_(gv[1]) * s_c[t] + sigmoidf_(gv[0]) * tanh_(gv[2]);
            const float hn = sigmoidf_(gv[3]) * tanh_(cn);
            s_c[t] = cn;
            s_h[t] = hn;
            s_xcat[259 + t] = hn;
        }
        __syncthreads();

        // ---- P7: pred[o] = Wo[o].h + bo[o]; feedback as next x_in ----
        if (wave < NOUT) {
            const float4 w4 = *(const float4*)&Wo[wave * HID + lane * 4];
            const float4 h4 = *(const float4*)&s_h[lane * 4];
            float p = w4.x * h4.x + w4.y * h4.y + w4.z * h4.z + w4.w * h4.w;
            #pragma unroll
            for (int off = 32; off >= 1; off >>= 1) p += __shfl_xor(p, off);
            if (lane == 0) {
                p += bo[wave];
                s_xcat[wave] = p;
                pred_out[((size_t)b * NPRED + n) * NOUT + wave] = p;
            }
        }
        __syncthreads();
    }

    if (t < HID) hid_out[b * HID + t] = s_h[t];
}

// ---------------------------------------------------------------------------
extern "C" void kernel_launch(void* const* d_in, const int* in_sizes, int n_in,
                              void* d_out, int out_size, void* d_ws, size_t ws_size,
                              hipStream_t stream) {
    const float* enc  = (const float*)d_in[0];
    const float* h0   = (const float*)d_in[1];
    const float* c0   = (const float*)d_in[2];
    const float* Wa   = (const float*)d_in[3];
    const float* ba   = (const float*)d_in[4];
    const float* Ua   = (const float*)d_in[5];
    const float* bua  = (const float*)d_in[6];
    const float* W_ih = (const float*)d_in[7];
    const float* W_hh = (const float*)d_in[8];
    const float* b_ih = (const float*)d_in[9];
    const float* b_hh = (const float*)d_in[10];
    const float* Wo   = (const float*)d_in[11];
    const float* bo   = (const float*)d_in[12];

    float* WaT    = (float*)d_ws;               // 65536 floats
    float* WcatT  = WaT + HID * HID;            // 527360 floats
    float* bias_g = WcatT + KCAT * GATES;       // 1024 floats (~2.27 MB total)

    float* pred_out = (float*)d_out;                    // [B,N,3]
    float* hid_out  = pred_out + BATCH * NPRED * NOUT;  // [1,B,H]
    float* attn_out = hid_out + BATCH * HID;            // [B,N,S]

    prep_kernel<<<dim3((KCAT * GATES + 255) / 256), dim3(256), 0, stream>>>(
        Wa, W_ih, W_hh, b_ih, b_hh, WaT, WcatT, bias_g);

    decoder_kernel<<<dim3(BATCH), dim3(1024), 0, stream>>>(
        enc, h0, c0, ba, Ua, bua, Wo, bo, WaT, WcatT, bias_g,
        pred_out, hid_out, attn_out);
}

// Round 3
// 2456.951 us; speedup vs baseline: 3.3090x; 1.6931x over previous
//
#include <hip/hip_runtime.h>
#include <math.h>

#define HID   256
#define SEQ   512
#define BATCH 256
#define NPRED 64
#define NOUT  3
#define KCAT  515    // 3 (x_in) + 256 (ctx) + 256 (h)
#define KPAD  528    // padded to 4*66*2 for bf16-pair split-K
#define NPAIR 264    // KPAD/2
#define GATES 1024

typedef unsigned int  u32;

__device__ __forceinline__ float sigmoidf_(float x) { return 1.0f / (1.0f + __expf(-x)); }
__device__ __forceinline__ float tanh_(float x)     { return 1.0f - 2.0f / (__expf(2.0f * x) + 1.0f); }

// bf16 helpers: pack fp32->bf16 (RNE), unpack lo/hi bf16 of a u32 to fp32.
__device__ __forceinline__ unsigned short f2bf(float f) {
    union { float f; u32 u; } c; c.f = f;
    u32 u = c.u + 0x7fffu + ((c.u >> 16) & 1u);
    return (unsigned short)(u >> 16);
}
__device__ __forceinline__ u32 pack2(float a, float b) {
    return (u32)f2bf(a) | ((u32)f2bf(b) << 16);
}
__device__ __forceinline__ float bl(u32 u) { union { u32 x; float f; } c; c.x = u << 16;        return c.f; }
__device__ __forceinline__ float bh(u32 u) { union { u32 x; float f; } c; c.x = u & 0xffff0000u; return c.f; }

// ---------------------------------------------------------------------------
// prep_wc: pack Wcat (k<259: W_ih col k; else W_hh col k-259; k>=515: 0) into
// bf16 k-pairs. Wc2[p][j] is a uint4: component q packs (w[2p][4j+q], w[2p+1][4j+q]).
// ---------------------------------------------------------------------------
__global__ void prep_wc(const float* __restrict__ W_ih,
                        const float* __restrict__ W_hh,
                        uint4* __restrict__ Wc2) {
    const int p = blockIdx.x;        // 0..263
    const int j = threadIdx.x;       // 0..255
    const int k0 = 2 * p, k1 = 2 * p + 1;
    u32 comp[4];
    #pragma unroll
    for (int q = 0; q < 4; ++q) {
        const int g = 4 * j + q;
        float w0 = 0.f, w1 = 0.f;
        if (k0 < KCAT) w0 = (k0 < 259) ? W_ih[g * 259 + k0] : W_hh[g * HID + (k0 - 259)];
        if (k1 < KCAT) w1 = (k1 < 259) ? W_ih[g * 259 + k1] : W_hh[g * HID + (k1 - 259)];
        comp[q] = pack2(w0, w1);
    }
    Wc2[p * 256 + j] = make_uint4(comp[0], comp[1], comp[2], comp[3]);
}

// ---------------------------------------------------------------------------
// prep_ma: MaT[k][j] = sum_m Wa[m][k]*Ua[m][j], packed as bf16 k-quads:
// Ma4[k4][j].x = pack(MaT[4k4][j], MaT[4k4+1][j]); .y = (+2, +3).
// ---------------------------------------------------------------------------
__global__ void prep_ma(const float* __restrict__ Wa,
                        const float* __restrict__ Ua,
                        uint2* __restrict__ Ma4) {
    const int k4 = blockIdx.x;       // 0..63
    const int j  = threadIdx.x;      // 0..255
    float acc[4] = {0.f, 0.f, 0.f, 0.f};
    for (int m = 0; m < HID; ++m) {
        const float ua = Ua[m * HID + j];
        #pragma unroll
        for (int q = 0; q < 4; ++q)
            acc[q] += Wa[m * HID + 4 * k4 + q] * ua;
    }
    Ma4[k4 * 256 + j] = make_uint2(pack2(acc[0], acc[1]), pack2(acc[2], acc[3]));
}

// ---------------------------------------------------------------------------
// prep_misc: bias_g[j] = b_ih[j]+b_hh[j];  v0[j] = sum_m ba[m]*Ua[m][j]
// ---------------------------------------------------------------------------
__global__ void prep_misc(const float* __restrict__ b_ih,
                          const float* __restrict__ b_hh,
                          const float* __restrict__ ba,
                          const float* __restrict__ Ua,
                          float* __restrict__ bias_g,
                          float* __restrict__ v0) {
    const int t = threadIdx.x;       // one block of 1024
    if (t < GATES) bias_g[t] = b_ih[t] + b_hh[t];
    if (t < HID) {
        float acc = 0.f;
        for (int m = 0; m < HID; ++m) acc += ba[m] * Ua[m * HID + t];
        v0[t] = acc;
    }
}

// ---------------------------------------------------------------------------
// prep_enc: fp32 enc -> bf16 (2 elems per u32), grid-stride over float4 groups.
// ---------------------------------------------------------------------------
__global__ void prep_enc(const float* __restrict__ enc, u32* __restrict__ enc_bf) {
    const int total = BATCH * SEQ * HID / 4;   // 8388608 float4 groups
    for (int i = blockIdx.x * blockDim.x + threadIdx.x; i < total;
         i += gridDim.x * blockDim.x) {
        const float4 f = ((const float4*)enc)[i];
        ((uint2*)enc_bf)[i] = make_uint2(pack2(f.x, f.y), pack2(f.z, f.w));
    }
}

// ---------------------------------------------------------------------------
// Persistent decoder: one 1024-thread block (16 waves) per batch element.
// Per step: vq GEMV (bf16 Ma) -> attention pass (bf16 enc) -> gates GEMV
// (bf16 Wcat) -> LSTM pointwise -> pred.
// ---------------------------------------------------------------------------
template <bool ENCBF>
__global__ __launch_bounds__(1024)
void decoder_kernel(const float* __restrict__ enc,     // [B,S,H] fp32
                    const u32*   __restrict__ enc_bf,  // [B,S,H] bf16 (2/u32)
                    const float* __restrict__ h0,
                    const float* __restrict__ c0,
                    const float* __restrict__ Wo,      // [3,H]
                    const float* __restrict__ bo,      // [3]
                    const uint2* __restrict__ Ma4,     // [64][256]
                    const float* __restrict__ v0,      // [256]
                    const uint4* __restrict__ Wc2,     // [264][256]
                    const float* __restrict__ bias_g,  // [1024]
                    float* __restrict__ pred_out,      // [B,N,3]
                    float* __restrict__ hid_out,       // [B,H]
                    float* __restrict__ attn_out)      // [B,N,S]
{
    const int b    = blockIdx.x;
    const int t    = threadIdx.x;
    const int wave = t >> 6;          // 0..15
    const int lane = t & 63;
    const int j    = t & 255;         // output index within 256-wide arrays
    const int ks   = t >> 8;          // 0..3 split-K slice

    __shared__ __align__(16) float s_h[HID], s_c[HID], s_vq[HID];
    __shared__ __align__(16) float s_xcat[KPAD];       // [x_in(3)|ctx(256)|h(256)|pad0]
    __shared__ __align__(16) float s_scores[SEQ];
    __shared__ __align__(16) float s_gp[4096];   // P3: [16][256] wave-ctx; P5: [4][1024]
    __shared__ __align__(16) float s_part[4][HID];
    __shared__ float s_wm[16], s_wl[16], s_M, s_invL;

    if (t < HID) {
        s_h[t] = h0[b * HID + t];
        s_c[t] = c0[b * HID + t];
        s_xcat[259 + t] = s_h[t];
        if (t < NOUT) s_xcat[t] = 0.0f;           // SOS token = 0
    }
    if (t < KPAD - KCAT) s_xcat[KCAT + t] = 0.0f; // zero pad rows
    __syncthreads();

    const float* encb    = enc    + (size_t)b * SEQ * HID;
    const u32*   encb_bf = ENCBF ? (enc_bf + (size_t)b * SEQ * (HID / 2)) : nullptr;

    for (int n = 0; n < NPRED; ++n) {
        // ---- P1: vq[j] = v0[j] + sum_k MaT[k][j] h[k]; 4-way split-K, bf16 quads ----
        {
            float acc = 0.0f;
            #pragma unroll 4
            for (int qq = 0; qq < 16; ++qq) {
                const int q = ks * 16 + qq;
                const uint2 u  = Ma4[q * 256 + j];
                const float4 h4 = *(const float4*)&s_h[4 * q];
                acc += bl(u.x) * h4.x + bh(u.x) * h4.y
                     + bl(u.y) * h4.z + bh(u.y) * h4.w;
            }
            s_part[ks][j] = acc;
        }
        __syncthreads();
        if (t < HID)
            s_vq[t] = v0[t] + s_part[0][t] + s_part[1][t] + s_part[2][t] + s_part[3][t];
        __syncthreads();

        // ---- P3: one pass over enc[b]; wave w handles rows w, w+16, ... ----
        const float4 vq4 = *(const float4*)&s_vq[lane * 4];
        float m = -INFINITY, lsum = 0.0f;
        float4 cacc = {0.f, 0.f, 0.f, 0.f};
        for (int s = wave; s < SEQ; s += 16) {
            float e0, e1, e2, e3;
            if (ENCBF) {
                const uint2 u = *(const uint2*)(encb_bf + s * (HID / 2) + lane * 2);
                e0 = bl(u.x); e1 = bh(u.x); e2 = bl(u.y); e3 = bh(u.y);
            } else {
                const float4 e4 = *(const float4*)&encb[s * HID + lane * 4];
                e0 = e4.x; e1 = e4.y; e2 = e4.z; e3 = e4.w;
            }
            float p = e0 * vq4.x + e1 * vq4.y + e2 * vq4.z + e3 * vq4.w;
            #pragma unroll
            for (int off = 32; off >= 1; off >>= 1) p += __shfl_xor(p, off);
            const float score = p;                 // bias-dot term dropped: softmax-invariant
            if (lane == 0) s_scores[s] = score;
            const float mnew  = fmaxf(m, score);
            const float alpha = __expf(m - mnew);  // first iter: exp(-inf)=0
            const float e     = __expf(score - mnew);
            lsum   = lsum * alpha + e;
            cacc.x = cacc.x * alpha + e0 * e;
            cacc.y = cacc.y * alpha + e1 * e;
            cacc.z = cacc.z * alpha + e2 * e;
            cacc.w = cacc.w * alpha + e3 * e;
            m = mnew;
        }
        *(float4*)&s_gp[wave * HID + lane * 4] = cacc;
        if (lane == 0) { s_wm[wave] = m; s_wl[wave] = lsum; }
        __syncthreads();

        // ---- combine 16 wave partials; write ctx ----
        if (t < HID) {
            float M = s_wm[0];
            #pragma unroll
            for (int w = 1; w < 16; ++w) M = fmaxf(M, s_wm[w]);
            float L = 0.0f, ctx = 0.0f;
            #pragma unroll
            for (int w = 0; w < 16; ++w) {
                const float a = __expf(s_wm[w] - M);
                L   += a * s_wl[w];
                ctx += a * s_gp[w * HID + t];
            }
            const float invL = 1.0f / L;
            s_xcat[3 + t] = ctx * invL;
            if (t == 0) { s_M = M; s_invL = invL; }
        }
        __syncthreads();

        // ---- attention weights out (t < 512) ----
        if (t < SEQ)
            attn_out[((size_t)b * NPRED + n) * SEQ + t] =
                __expf(s_scores[t] - s_M) * s_invL;

        // ---- P5: gate partials; 4-way split over 66 bf16 k-pairs each ----
        {
            float4 g4 = {0.f, 0.f, 0.f, 0.f};
            const int pbeg = ks * 66;
            #pragma unroll 2
            for (int pp = 0; pp < 66; ++pp) {
                const int p = pbeg + pp;
                const uint4  w  = Wc2[p * 256 + j];
                const float2 xk = *(const float2*)&s_xcat[2 * p];
                g4.x += xk.x * bl(w.x) + xk.y * bh(w.x);
                g4.y += xk.x * bl(w.y) + xk.y * bh(w.y);
                g4.z += xk.x * bl(w.z) + xk.y * bh(w.z);
                g4.w += xk.x * bl(w.w) + xk.y * bh(w.w);
            }
            *(float4*)&s_gp[ks * GATES + j * 4] = g4;
        }
        __syncthreads();

        // ---- finalize gates + LSTM pointwise (unit t); gate order i,f,g,o ----
        if (t < HID) {
            float gv[4];
            #pragma unroll
            for (int q = 0; q < 4; ++q) {
                const int gi = q * HID + t;
                gv[q] = bias_g[gi] + s_gp[gi] + s_gp[GATES + gi]
                      + s_gp[2 * GATES + gi] + s_gp[3 * GATES + gi];
            }
            const float cn = sigmoidf_(gv[1]) * s_c[t] + sigmoidf_(gv[0]) * tanh_(gv[2]);
            const float hn = sigmoidf_(gv[3]) * tanh_(cn);
            s_c[t] = cn;
            s_h[t] = hn;
            s_xcat[259 + t] = hn;
        }
        __syncthreads();

        // ---- P7: pred[o] = Wo[o].h + bo[o]; feedback as next x_in ----
        if (wave < NOUT) {
            const float4 w4 = *(const float4*)&Wo[wave * HID + lane * 4];
            const float4 h4 = *(const float4*)&s_h[lane * 4];
            float p = w4.x * h4.x + w4.y * h4.y + w4.z * h4.z + w4.w * h4.w;
            #pragma unroll
            for (int off = 32; off >= 1; off >>= 1) p += __shfl_xor(p, off);
            if (lane == 0) {
                p += bo[wave];
                s_xcat[wave] = p;
                pred_out[((size_t)b * NPRED + n) * NOUT + wave] = p;
            }
        }
        __syncthreads();
    }

    if (t < HID) hid_out[b * HID + t] = s_h[t];
}

// ---------------------------------------------------------------------------
extern "C" void kernel_launch(void* const* d_in, const int* in_sizes, int n_in,
                              void* d_out, int out_size, void* d_ws, size_t ws_size,
                              hipStream_t stream) {
    const float* enc  = (const float*)d_in[0];
    const float* h0   = (const float*)d_in[1];
    const float* c0   = (const float*)d_in[2];
    const float* Wa   = (const float*)d_in[3];
    const float* ba   = (const float*)d_in[4];
    const float* Ua   = (const float*)d_in[5];
    // d_in[6] = bua: dropped — its score contribution is constant over s (softmax-invariant)
    const float* W_ih = (const float*)d_in[7];
    const float* W_hh = (const float*)d_in[8];
    const float* b_ih = (const float*)d_in[9];
    const float* b_hh = (const float*)d_in[10];
    const float* Wo   = (const float*)d_in[11];
    const float* bo   = (const float*)d_in[12];

    char* ws = (char*)d_ws;
    uint4* Wc2    = (uint4*)ws;                      ws += (size_t)NPAIR * 256 * 16; // 1,081,344
    uint2* Ma4    = (uint2*)ws;                      ws += (size_t)64 * 256 * 8;     //   131,072
    float* v0     = (float*)ws;                      ws += 256 * 4;
    float* bias_g = (float*)ws;                      ws += GATES * 4;
    const size_t base = (size_t)(ws - (char*)d_ws);
    const size_t enc_bf_bytes = (size_t)BATCH * SEQ * HID * 2;   // 67,108,864
    const bool use_encbf = ws_size >= base + enc_bf_bytes;
    u32* enc_bf = (u32*)ws;

    float* pred_out = (float*)d_out;                    // [B,N,3]
    float* hid_out  = pred_out + BATCH * NPRED * NOUT;  // [1,B,H]
    float* attn_out = hid_out + BATCH * HID;            // [B,N,S]

    prep_wc  <<<dim3(NPAIR), dim3(256),  0, stream>>>(W_ih, W_hh, Wc2);
    prep_ma  <<<dim3(64),    dim3(256),  0, stream>>>(Wa, Ua, Ma4);
    prep_misc<<<dim3(1),     dim3(1024), 0, stream>>>(b_ih, b_hh, ba, Ua, bias_g, v0);
    if (use_encbf) {
        prep_enc<<<dim3(2048), dim3(256), 0, stream>>>(enc, enc_bf);
        decoder_kernel<true><<<dim3(BATCH), dim3(1024), 0, stream>>>(
            enc, enc_bf, h0, c0, Wo, bo, Ma4, v0, Wc2, bias_g,
            pred_out, hid_out, attn_out);
    } else {
        decoder_kernel<false><<<dim3(BATCH), dim3(1024), 0, stream>>>(
            enc, enc_bf, h0, c0, Wo, bo, Ma4, v0, Wc2, bias_g,
            pred_out, hid_out, attn_out);
    }
}